// Round 4
// baseline (1504.481 us; speedup 1.0000x reference)
//
#include <hip/hip_runtime.h>
#include <hip/hip_bf16.h>
#include <math.h>

typedef _Float16 f16;
typedef __attribute__((ext_vector_type(8))) _Float16 f16x8;
typedef __attribute__((ext_vector_type(4))) float f32x4;

#define TOKENS 65536
#define D_ 512
#define F_ 1024
#define E_ 8
#define DT_ 16
#define TEMP_ 1.0f
#define RANKBIT (1 << 30)

// ---- workspace layout (bytes) ----
#define OFF_CNT   0                              // 8 ints
#define OFF_IMP   64                             // 8 floats
#define OFF_TOK   4096                           // [E][TOKENS] int (rank bit 30)
#define OFF_GATE  (OFF_TOK  + E_*TOKENS*4)
#define OFF_W1P   (OFF_GATE + E_*TOKENS*4)       // packed W1 f16, 8 MB
#define OFF_W2P   (OFF_W1P  + E_*F_*D_*2)        // packed W2 f16, 8 MB
#define OFF_REC1  (OFF_W2P  + E_*F_*D_*2)        // rank-1 gated outputs, f16 [TOKENS][D], 67 MB
#define REC1_BYTES ((size_t)TOKENS * D_ * 2)
#define WS_NEED   ((size_t)OFF_REC1 + REC1_BYTES)

// ---------------------------------------------------------------------------
// Pack src [E][R][C] f32 (R=K, C=N) into MFMA-B fragment order:
// dst [E][C/16][R/32][64 lane][8 f16]; lane l holds col (l&15), k (l>>4)*8+j.
// ---------------------------------------------------------------------------
__global__ __launch_bounds__(256) void k_pack(const float* __restrict__ src,
                                              f16* __restrict__ dst, int R, int C)
{
  int e = blockIdx.y, ct = blockIdx.x;
  int tid = threadIdx.x;
  int c = tid & 15, r8 = tid >> 4;
  const float* s = src + (size_t)e * R * C + (size_t)ct * 16 + c;
  f16* d = dst + ((size_t)e * (C / 16) + ct) * (size_t)(R / 32) * 512;
  int passes = R / 128;
  for (int p = 0; p < passes; ++p) {
    int k0 = (p * 16 + r8) * 8;
    int ks = k0 >> 5, lg = (k0 >> 3) & 3;
    f16x8 v;
    #pragma unroll
    for (int j = 0; j < 8; ++j) v[j] = (f16)s[(size_t)(k0 + j) * C];
    *(f16x8*)(d + (size_t)ks * 512 + (size_t)(c + 16 * lg) * 8) = v;
  }
}

// ---------------------------------------------------------------------------
// Router: fp32 logits, top-2, gates, aux partials, dispatch lists.
// tokrec entry: token | (rank<<30).
// ---------------------------------------------------------------------------
__global__ __launch_bounds__(256) void k_router(
    const float* __restrict__ x, const float* __restrict__ z, const float* __restrict__ tau,
    const float* __restrict__ Wr, const float* __restrict__ br,
    int* __restrict__ gcnt, float* __restrict__ gimp,
    int* __restrict__ tokrec, float* __restrict__ gaterec)
{
  __shared__ float zlog[E_];
  __shared__ float stau;
  __shared__ int   recI[128];
  __shared__ float rg0[128], rg1[128];
  __shared__ int   pos0[128], pos1[128];
  __shared__ int   lcnt[E_], lbase[E_];
  __shared__ float limp[E_];

  int tid = threadIdx.x, lane = tid & 63, w = tid >> 6;
  int t0 = blockIdx.x * 128;
  int b = t0 >> 11;

  if (tid < E_) {
    float s = br[tid];
    #pragma unroll
    for (int dt = 0; dt < DT_; ++dt) s += z[b * DT_ + dt] * Wr[(D_ + dt) * E_ + tid];
    zlog[tid] = s;
    lcnt[tid] = 0; limp[tid] = 0.f;
  }
  if (tid == 0) stau = TEMP_ * tau[b];

  float wreg[8][8];
  const float* wp = Wr + lane * 64;
  #pragma unroll
  for (int j = 0; j < 8; ++j) {
    f32x4 a = *(const f32x4*)(wp + j * 8);
    f32x4 c = *(const f32x4*)(wp + j * 8 + 4);
    wreg[j][0]=a[0]; wreg[j][1]=a[1]; wreg[j][2]=a[2]; wreg[j][3]=a[3];
    wreg[j][4]=c[0]; wreg[j][5]=c[1]; wreg[j][6]=c[2]; wreg[j][7]=c[3];
  }
  __syncthreads();
  float tv = stau;
  float imp[E_];
  #pragma unroll
  for (int e2 = 0; e2 < E_; ++e2) imp[e2] = 0.f;

  for (int i = 0; i < 32; ++i) {
    int li = w * 32 + i;
    int t = t0 + li;
    const float* xr = x + (size_t)t * D_ + lane * 8;
    f32x4 xa = *(const f32x4*)xr;
    f32x4 xb = *(const f32x4*)(xr + 4);
    float v[E_];
    #pragma unroll
    for (int e2 = 0; e2 < E_; ++e2)
      v[e2] = xa[0]*wreg[0][e2] + xa[1]*wreg[1][e2] + xa[2]*wreg[2][e2] + xa[3]*wreg[3][e2]
            + xb[0]*wreg[4][e2] + xb[1]*wreg[5][e2] + xb[2]*wreg[6][e2] + xb[3]*wreg[7][e2];
    #pragma unroll
    for (int s = 0; s < 6; ++s) {
      #pragma unroll
      for (int e2 = 0; e2 < E_; ++e2) v[e2] += __shfl_xor(v[e2], 1 << s, 64);
    }
    if (lane == 0) {
      #pragma unroll
      for (int e2 = 0; e2 < E_; ++e2) v[e2] = (v[e2] + zlog[e2]) / tv;
      int i0 = 0; float b0v = v[0];
      #pragma unroll
      for (int e2 = 1; e2 < E_; ++e2) if (v[e2] > b0v) { b0v = v[e2]; i0 = e2; }
      int i1 = -1; float b1v = -3.4e38f;
      #pragma unroll
      for (int e2 = 0; e2 < E_; ++e2) if (e2 != i0 && v[e2] > b1v) { b1v = v[e2]; i1 = e2; }
      float ee = expf(b1v - b0v);
      float g0 = 1.f / (1.f + ee);
      recI[li] = i0 | (i1 << 4);
      rg0[li] = g0; rg1[li] = ee * g0;
      float ssum = 0.f, pe[E_];
      #pragma unroll
      for (int e2 = 0; e2 < E_; ++e2) { pe[e2] = expf(v[e2] - b0v); ssum += pe[e2]; }
      float inv = 1.f / ssum;
      #pragma unroll
      for (int e2 = 0; e2 < E_; ++e2) imp[e2] += pe[e2] * inv;
    }
  }
  if (lane == 0) {
    #pragma unroll
    for (int e2 = 0; e2 < E_; ++e2) atomicAdd(&limp[e2], imp[e2]);
  }
  __syncthreads();
  if (tid < 128) {
    int r = recI[tid], i0 = r & 15, i1 = r >> 4;
    pos0[tid] = atomicAdd(&lcnt[i0], 1);
    pos1[tid] = atomicAdd(&lcnt[i1], 1);
  }
  __syncthreads();
  if (tid < E_) {
    lbase[tid] = atomicAdd(&gcnt[tid], lcnt[tid]);
    atomicAdd(&gimp[tid], limp[tid]);
  }
  __syncthreads();
  if (tid < 128) {
    int r = recI[tid], i0 = r & 15, i1 = r >> 4;
    int t = t0 + tid;
    int o0 = i0 * TOKENS + lbase[i0] + pos0[tid];
    int o1 = i1 * TOKENS + lbase[i1] + pos1[tid];
    tokrec[o0] = t;            gaterec[o0] = rg0[tid];
    tokrec[o1] = t | RANKBIT;  gaterec[o1] = rg1[tid];
  }
}

// branchless gelu (erf via A&S 7.1.26, |eps|~1e-6 << f16 ulp)
__device__ __forceinline__ float gelu_f(float v)
{
  float u = v * 0.70710678118654752f;
  float au = fabsf(u);
  float t = __builtin_amdgcn_rcpf(1.f + 0.3275911f * au);
  float p = t * (0.254829592f + t * (-0.284496736f + t * (1.421413741f +
            t * (-1.453152027f + t * 1.061405429f))));
  float er = 1.f - p * __expf(-u * u);
  return 0.5f * v * (1.f + copysignf(er, v));
}

// ---------------------------------------------------------------------------
// Fused expert MLP. Per iter: F-chunk 128, wave w owns coltile it*8+w for all
// 64 rows (W1 fragments reused 4x, zero duplication). Epilogue: rank0 -> f32
// direct store to y, rank1 -> f16 rec1[token]; atomic fallback if ws small.
// ---------------------------------------------------------------------------
__global__ __launch_bounds__(512, 4) void k_mlp(
    const float* __restrict__ x,
    const f16* __restrict__ W1p, const float* __restrict__ b1,
    const f16* __restrict__ W2p, const float* __restrict__ b2,
    const int* __restrict__ gcnt, const int* __restrict__ tokrec,
    const float* __restrict__ gaterec,
    f16* __restrict__ rec1, float* __restrict__ y, int use_rec)
{
  int e    = blockIdx.x & 7;       // XCD pin
  int tile = blockIdx.x >> 3;
  int cnt  = gcnt[e];
  int start = tile * 64;
  if (start >= cnt) return;

  __shared__ f16 xs[64 * 512];     // 64 KB
  __shared__ f16 hs[64 * 128];     // 16 KB  (total 80 KB -> 2 blocks/CU)

  int tid = threadIdx.x, lane = tid & 63, w = tid >> 6;
  int l15 = lane & 15, lk8 = (lane >> 4) * 8;

  const int*   tokE  = tokrec  + e * TOKENS;
  const float* gateE = gaterec + e * TOKENS;

  // gather + convert x rows into LDS (nontemporal: don't evict weights from L2)
  for (int r = w; r < 64; r += 8) {
    int ridx = start + r;
    f32x4 a = {0.f,0.f,0.f,0.f}, bv = {0.f,0.f,0.f,0.f};
    if (ridx < cnt) {
      int tk = tokE[ridx] & 0x3FFFFFFF;
      const float* p = x + (size_t)tk * D_ + lane * 8;
      a  = __builtin_nontemporal_load((const f32x4*)p);
      bv = __builtin_nontemporal_load((const f32x4*)(p + 4));
    }
    f16x8 pk;
    pk[0]=(f16)a[0];  pk[1]=(f16)a[1];  pk[2]=(f16)a[2];  pk[3]=(f16)a[3];
    pk[4]=(f16)bv[0]; pk[5]=(f16)bv[1]; pk[6]=(f16)bv[2]; pk[7]=(f16)bv[3];
    int off = (r * 1024 + lane * 16) ^ ((r & 7) << 4);
    *(f16x8*)((char*)xs + off) = pk;
  }
  __syncthreads();

  f32x4 yacc[4][4];
  #pragma unroll
  for (int mt = 0; mt < 4; ++mt)
    #pragma unroll
    for (int nt = 0; nt < 4; ++nt) {
      yacc[mt][nt][0]=0.f; yacc[mt][nt][1]=0.f; yacc[mt][nt][2]=0.f; yacc[mt][nt][3]=0.f;
    }

  const f16* w1b = W1p + (size_t)e * (64 * 16 * 512);
  const f16* w2b = W2p + (size_t)e * (32 * 32 * 512);
  int ct2base = w * 4;

  for (int it = 0; it < 8; ++it) {
    int ct = it * 8 + w;                       // this wave's F-coltile
    float b1v = b1[e * F_ + ct * 16 + l15];
    const f16* pA = w1b + ((size_t)ct * 16) * 512 + lane * 8;

    // ---- stage A: H[64 x 16] = x_tile @ W1 coltile ----
    f32x4 hA[4];
    #pragma unroll
    for (int mt = 0; mt < 4; ++mt) { hA[mt][0]=0.f; hA[mt][1]=0.f; hA[mt][2]=0.f; hA[mt][3]=0.f; }
    #pragma unroll
    for (int ks = 0; ks < 16; ++ks) {
      f16x8 wf = *(const f16x8*)(pA + (size_t)ks * 512);
      int k0 = ks * 32 + lk8;
      #pragma unroll
      for (int mt = 0; mt < 4; ++mt) {
        int arow = mt * 16 + l15;
        int aoff = (arow * 1024 + k0 * 2) ^ ((arow & 7) << 4);
        f16x8 af = *(const f16x8*)((const char*)xs + aoff);
        hA[mt] = __builtin_amdgcn_mfma_f32_16x16x32_f16(af, wf, hA[mt], 0, 0, 0);
      }
    }

    // prefetch stage-B ks=0 fragments (latency hides under gelu VALU)
    f16x8 preB[4];
    #pragma unroll
    for (int nt = 0; nt < 4; ++nt)
      preB[nt] = *(const f16x8*)(w2b + ((size_t)(ct2base + nt) * 32 + it * 4) * 512 + lane * 8);

    // gelu in place
    #pragma unroll
    for (int mt = 0; mt < 4; ++mt)
      #pragma unroll
      for (int rg = 0; rg < 4; ++rg)
        hA[mt][rg] = gelu_f(hA[mt][rg] + b1v);

    __syncthreads();   // all waves done reading hs of previous iter
    #pragma unroll
    for (int mt = 0; mt < 4; ++mt) {
      #pragma unroll
      for (int rg = 0; rg < 4; ++rg) {
        int row = mt * 16 + ((lane >> 4) << 2) + rg;
        int colg = w * 16 + l15;
        int off = (row * 256 + colg * 2) ^ ((row & 7) << 4);
        *(f16*)((char*)hs + off) = (f16)hA[mt][rg];
      }
    }
    __syncthreads();   // hs ready

    // ---- stage B: yacc += H @ W2 chunk (K = 128) ----
    #pragma unroll
    for (int ks = 0; ks < 4; ++ks) {
      f16x8 wfB[4];
      if (ks == 0) {
        #pragma unroll
        for (int nt = 0; nt < 4; ++nt) wfB[nt] = preB[nt];
      } else {
        #pragma unroll
        for (int nt = 0; nt < 4; ++nt)
          wfB[nt] = *(const f16x8*)(w2b + ((size_t)(ct2base + nt) * 32 + it * 4 + ks) * 512 + lane * 8);
      }
      f16x8 afr[4];
      #pragma unroll
      for (int mt = 0; mt < 4; ++mt) {
        int arow = mt * 16 + l15;
        int aoff = (arow * 256 + (ks * 32 + lk8) * 2) ^ ((arow & 7) << 4);
        afr[mt] = *(const f16x8*)((const char*)hs + aoff);
      }
      #pragma unroll
      for (int nt = 0; nt < 4; ++nt)
        #pragma unroll
        for (int mt = 0; mt < 4; ++mt)
          yacc[mt][nt] = __builtin_amdgcn_mfma_f32_16x16x32_f16(afr[mt], wfB[nt], yacc[mt][nt], 0, 0, 0);
    }
  }

  // ---- epilogue ----
  float b2s[4];
  #pragma unroll
  for (int nt = 0; nt < 4; ++nt) b2s[nt] = b2[e * D_ + w * 64 + nt * 16 + l15];

  if (use_rec) {
    #pragma unroll
    for (int mt = 0; mt < 4; ++mt) {
      #pragma unroll
      for (int rg = 0; rg < 4; ++rg) {
        int row = mt * 16 + ((lane >> 4) << 2) + rg;
        int ridx = start + row;
        if (ridx < cnt) {
          int trec = tokE[ridx];
          float g  = gateE[ridx];
          size_t tk = (size_t)(trec & 0x3FFFFFFF);
          if (trec & RANKBIT) {
            #pragma unroll
            for (int nt = 0; nt < 4; ++nt) {
              f16 hv = (f16)(g * (yacc[mt][nt][rg] + b2s[nt]));
              __builtin_nontemporal_store(hv, rec1 + tk * D_ + w * 64 + nt * 16 + l15);
            }
          } else {
            #pragma unroll
            for (int nt = 0; nt < 4; ++nt)
              __builtin_nontemporal_store(g * (yacc[mt][nt][rg] + b2s[nt]),
                                          y + tk * D_ + w * 64 + nt * 16 + l15);
          }
        }
      }
    }
  } else {
    #pragma unroll
    for (int mt = 0; mt < 4; ++mt) {
      #pragma unroll
      for (int rg = 0; rg < 4; ++rg) {
        int row = mt * 16 + ((lane >> 4) << 2) + rg;
        int ridx = start + row;
        if (ridx < cnt) {
          int trec = tokE[ridx];
          float g  = gateE[ridx];
          size_t tk = (size_t)(trec & 0x3FFFFFFF);
          float* yp = y + tk * D_ + w * 64 + l15;
          #pragma unroll
          for (int nt = 0; nt < 4; ++nt)
            atomicAdd(yp + nt * 16, g * (yacc[mt][nt][rg] + b2s[nt]));
        }
      }
    }
  }
}

// ---------------------------------------------------------------------------
// y[t] += rec1[t]  (streaming; rank0 already in y, rank1 gated in rec1)
// ---------------------------------------------------------------------------
__global__ __launch_bounds__(256) void k_combine(const f16* __restrict__ rec1,
                                                 float* __restrict__ y)
{
  size_t i = (size_t)blockIdx.x * 256 + threadIdx.x;
  size_t n = (size_t)TOKENS * (D_ / 8);
  size_t stride = (size_t)gridDim.x * 256;
  for (; i < n; i += stride) {
    f16x8 r = __builtin_nontemporal_load((const f16x8*)rec1 + i);
    float* yp = y + i * 8;
    f32x4 lo = __builtin_nontemporal_load((const f32x4*)yp);
    f32x4 hi = __builtin_nontemporal_load((const f32x4*)yp + 1);
    lo[0] += (float)r[0]; lo[1] += (float)r[1]; lo[2] += (float)r[2]; lo[3] += (float)r[3];
    hi[0] += (float)r[4]; hi[1] += (float)r[5]; hi[2] += (float)r[6]; hi[3] += (float)r[7];
    __builtin_nontemporal_store(lo, (f32x4*)yp);
    __builtin_nontemporal_store(hi, (f32x4*)yp + 1);
  }
}

// ---------------------------------------------------------------------------
__global__ void k_aux(const int* __restrict__ gcnt, const float* __restrict__ gimp,
                      float* __restrict__ outp)
{
  if (threadIdx.x == 0) {
    float a = 0.f;
    for (int e2 = 0; e2 < E_; ++e2)
      a += ((float)gcnt[e2] * (1.f / 65536.f)) * (gimp[e2] * (1.f / 65536.f));
    outp[0] = (float)E_ * a;
  }
}

extern "C" void kernel_launch(void* const* d_in, const int* in_sizes, int n_in,
                              void* d_out, int out_size, void* d_ws, size_t ws_size,
                              hipStream_t stream)
{
  const float* x   = (const float*)d_in[0];
  const float* z   = (const float*)d_in[1];
  const float* tau = (const float*)d_in[2];
  const float* Wr  = (const float*)d_in[3];
  const float* br  = (const float*)d_in[4];
  const float* W1  = (const float*)d_in[5];
  const float* b1  = (const float*)d_in[6];
  const float* W2  = (const float*)d_in[7];
  const float* b2  = (const float*)d_in[8];
  float* out = (float*)d_out;
  char*  ws  = (char*)d_ws;

  int*   gcnt    = (int*)  (ws + OFF_CNT);
  float* gimp    = (float*)(ws + OFF_IMP);
  int*   tokrec  = (int*)  (ws + OFF_TOK);
  float* gaterec = (float*)(ws + OFF_GATE);
  f16*   W1p     = (f16*)  (ws + OFF_W1P);
  f16*   W2p     = (f16*)  (ws + OFF_W2P);
  f16*   rec1    = (f16*)  (ws + OFF_REC1);

  int use_rec = (ws_size >= WS_NEED) ? 1 : 0;

  hipMemsetAsync(ws, 0, 4096, stream);                        // counters
  if (!use_rec)
    hipMemsetAsync(d_out, 0, (size_t)out_size * 4, stream);   // y for atomics

  k_pack<<<dim3(F_/16, E_), 256, 0, stream>>>(W1, W1p, D_, F_); // K=D, N=F
  k_pack<<<dim3(D_/16, E_), 256, 0, stream>>>(W2, W2p, F_, D_); // K=F, N=D

  k_router<<<TOKENS / 128, 256, 0, stream>>>(x, z, tau, Wr, br, gcnt, gimp,
                                             tokrec, gaterec);

  k_mlp<<<E_ * 1024, 512, 0, stream>>>(x, W1p, b1, W2p, b2, gcnt,
                                       tokrec, gaterec, rec1, out, use_rec);

  if (use_rec)
    k_combine<<<2048, 256, 0, stream>>>(rec1, out);

  k_aux<<<1, 64, 0, stream>>>(gcnt, gimp, out + (size_t)TOKENS * D_);
}

// Round 5
// 924.455 us; speedup vs baseline: 1.6274x; 1.6274x over previous
//
#include <hip/hip_runtime.h>
#include <hip/hip_bf16.h>
#include <math.h>

typedef _Float16 f16;
typedef __attribute__((ext_vector_type(8))) _Float16 f16x8;
typedef __attribute__((ext_vector_type(4))) float f32x4;

#define TOKENS 65536
#define D_ 512
#define F_ 1024
#define E_ 8
#define DT_ 16
#define TEMP_ 1.0f
#define RANKBIT (1 << 30)

// ---- workspace layout (bytes) ----
#define OFF_CNT   0                              // 8 ints
#define OFF_IMP   64                             // 8 floats
#define OFF_TOK   4096                           // [E][TOKENS] int (rank bit 30)
#define OFF_GATE  (OFF_TOK  + E_*TOKENS*4)
#define OFF_W1P   (OFF_GATE + E_*TOKENS*4)       // packed W1 f16, 8 MB
#define OFF_W2P   (OFF_W1P  + E_*F_*D_*2)        // packed W2 f16, 8 MB
#define OFF_REC1  (OFF_W2P  + E_*F_*D_*2)        // rank-1 gated outputs f16 [TOKENS][D]
#define REC1_BYTES ((size_t)TOKENS * D_ * 2)
#define WS_NEED   ((size_t)OFF_REC1 + REC1_BYTES)

// ---------------------------------------------------------------------------
// Pack src [E][R][C] f32 (R=K, C=N) into MFMA-B fragment order
// dst [E][C/16][R/32][512] f16 : dst[e][ct][ks][l*8+j] = src[e][ks*32+(l>>4)*8+j][ct*16+(l&15)]
// LDS-tiled: coalesced global reads, contiguous 1KB fragment writes.
// ---------------------------------------------------------------------------
__global__ __launch_bounds__(256) void k_pack(const float* __restrict__ src,
                                              f16* __restrict__ dst, int R, int C)
{
  __shared__ float tile[128][17];
  int e = blockIdx.z, ct = blockIdx.y, kp = blockIdx.x;
  const float* s = src + (size_t)e * R * C + (size_t)(kp * 128) * C + ct * 16;
  int t = threadIdx.x;
  int c = t & 15, r0 = t >> 4;
  #pragma unroll
  for (int p = 0; p < 8; ++p)
    tile[r0 + p * 16][c] = s[(size_t)(r0 + p * 16) * C + c];
  __syncthreads();
  int ksl = t >> 6, l = t & 63, l15 = l & 15, lq = l >> 4;
  f16x8 v;
  #pragma unroll
  for (int j = 0; j < 8; ++j) v[j] = (f16)tile[ksl * 32 + lq * 8 + j][l15];
  f16* d = dst + ((((size_t)e * (C / 16) + ct) * (R / 32)) + kp * 4 + ksl) * 512 + l * 8;
  *(f16x8*)d = v;
}

// ---------------------------------------------------------------------------
// Router: fp32 logits, top-2, gates, aux partials, dispatch lists.
// tokrec entry: token | (rank<<30).
// ---------------------------------------------------------------------------
__global__ __launch_bounds__(256) void k_router(
    const float* __restrict__ x, const float* __restrict__ z, const float* __restrict__ tau,
    const float* __restrict__ Wr, const float* __restrict__ br,
    int* __restrict__ gcnt, float* __restrict__ gimp,
    int* __restrict__ tokrec, float* __restrict__ gaterec)
{
  __shared__ float zlog[E_];
  __shared__ float stau;
  __shared__ int   recI[128];
  __shared__ float rg0[128], rg1[128];
  __shared__ int   pos0[128], pos1[128];
  __shared__ int   lcnt[E_], lbase[E_];
  __shared__ float limp[E_];

  int tid = threadIdx.x, lane = tid & 63, w = tid >> 6;
  int t0 = blockIdx.x * 128;
  int b = t0 >> 11;

  if (tid < E_) {
    float s = br[tid];
    #pragma unroll
    for (int dt = 0; dt < DT_; ++dt) s += z[b * DT_ + dt] * Wr[(D_ + dt) * E_ + tid];
    zlog[tid] = s;
    lcnt[tid] = 0; limp[tid] = 0.f;
  }
  if (tid == 0) stau = TEMP_ * tau[b];

  float wreg[8][8];
  const float* wp = Wr + lane * 64;
  #pragma unroll
  for (int j = 0; j < 8; ++j) {
    f32x4 a = *(const f32x4*)(wp + j * 8);
    f32x4 c = *(const f32x4*)(wp + j * 8 + 4);
    wreg[j][0]=a[0]; wreg[j][1]=a[1]; wreg[j][2]=a[2]; wreg[j][3]=a[3];
    wreg[j][4]=c[0]; wreg[j][5]=c[1]; wreg[j][6]=c[2]; wreg[j][7]=c[3];
  }
  __syncthreads();
  float tv = stau;
  float imp[E_];
  #pragma unroll
  for (int e2 = 0; e2 < E_; ++e2) imp[e2] = 0.f;

  for (int i = 0; i < 32; ++i) {
    int li = w * 32 + i;
    int t = t0 + li;
    const float* xr = x + (size_t)t * D_ + lane * 8;
    f32x4 xa = *(const f32x4*)xr;
    f32x4 xb = *(const f32x4*)(xr + 4);
    float v[E_];
    #pragma unroll
    for (int e2 = 0; e2 < E_; ++e2)
      v[e2] = xa[0]*wreg[0][e2] + xa[1]*wreg[1][e2] + xa[2]*wreg[2][e2] + xa[3]*wreg[3][e2]
            + xb[0]*wreg[4][e2] + xb[1]*wreg[5][e2] + xb[2]*wreg[6][e2] + xb[3]*wreg[7][e2];
    #pragma unroll
    for (int s = 0; s < 6; ++s) {
      #pragma unroll
      for (int e2 = 0; e2 < E_; ++e2) v[e2] += __shfl_xor(v[e2], 1 << s, 64);
    }
    if (lane == 0) {
      #pragma unroll
      for (int e2 = 0; e2 < E_; ++e2) v[e2] = (v[e2] + zlog[e2]) / tv;
      int i0 = 0; float b0v = v[0];
      #pragma unroll
      for (int e2 = 1; e2 < E_; ++e2) if (v[e2] > b0v) { b0v = v[e2]; i0 = e2; }
      int i1 = -1; float b1v = -3.4e38f;
      #pragma unroll
      for (int e2 = 0; e2 < E_; ++e2) if (e2 != i0 && v[e2] > b1v) { b1v = v[e2]; i1 = e2; }
      float ee = expf(b1v - b0v);
      float g0 = 1.f / (1.f + ee);
      recI[li] = i0 | (i1 << 4);
      rg0[li] = g0; rg1[li] = ee * g0;
      float ssum = 0.f, pe[E_];
      #pragma unroll
      for (int e2 = 0; e2 < E_; ++e2) { pe[e2] = expf(v[e2] - b0v); ssum += pe[e2]; }
      float inv = 1.f / ssum;
      #pragma unroll
      for (int e2 = 0; e2 < E_; ++e2) imp[e2] += pe[e2] * inv;
    }
  }
  if (lane == 0) {
    #pragma unroll
    for (int e2 = 0; e2 < E_; ++e2) atomicAdd(&limp[e2], imp[e2]);
  }
  __syncthreads();
  if (tid < 128) {
    int r = recI[tid], i0 = r & 15, i1 = r >> 4;
    pos0[tid] = atomicAdd(&lcnt[i0], 1);
    pos1[tid] = atomicAdd(&lcnt[i1], 1);
  }
  __syncthreads();
  if (tid < E_) {
    lbase[tid] = atomicAdd(&gcnt[tid], lcnt[tid]);
    atomicAdd(&gimp[tid], limp[tid]);
  }
  __syncthreads();
  if (tid < 128) {
    int r = recI[tid], i0 = r & 15, i1 = r >> 4;
    int t = t0 + tid;
    int o0 = i0 * TOKENS + lbase[i0] + pos0[tid];
    int o1 = i1 * TOKENS + lbase[i1] + pos1[tid];
    tokrec[o0] = t;            gaterec[o0] = rg0[tid];
    tokrec[o1] = t | RANKBIT;  gaterec[o1] = rg1[tid];
  }
}

// branchless gelu (erf via A&S 7.1.26, |eps|~1.5e-7)
__device__ __forceinline__ float gelu_f(float v)
{
  float u = v * 0.70710678118654752f;
  float au = fabsf(u);
  float t = __builtin_amdgcn_rcpf(1.f + 0.3275911f * au);
  float p = t * (0.254829592f + t * (-0.284496736f + t * (1.421413741f +
            t * (-1.453152027f + t * 1.061405429f))));
  float er = 1.f - p * __expf(-u * u);
  return 0.5f * v * (1.f + copysignf(er, v));
}

// ---------------------------------------------------------------------------
// Fused expert MLP. Token tile 128, 1024 threads (16 waves), 1 block/CU.
// XCD-pinned expert. F-chunk 64 per iter (16 iters).
// Stage A: wave (rga=w>>2 row-group of 32, cta=w&3 coltile): W1 frag reused 2x.
// Stage B: wave (rgb=w>>3 row-half of 64, csb=w&7 col-slice of 64).
// Epilogue: gated f16 rows via xs bounce -> full-row coalesced stores.
// ---------------------------------------------------------------------------
__global__ __launch_bounds__(1024, 4) void k_mlp(
    const float* __restrict__ x,
    const f16* __restrict__ W1p, const float* __restrict__ b1,
    const f16* __restrict__ W2p, const float* __restrict__ b2,
    const int* __restrict__ gcnt, const int* __restrict__ tokrec,
    const float* __restrict__ gaterec,
    f16* __restrict__ rec1, float* __restrict__ y, int use_rec)
{
  int e    = blockIdx.x & 7;       // XCD pin
  int tile = blockIdx.x >> 3;
  int cnt  = gcnt[e];
  int start = tile * 128;
  if (start >= cnt) return;

  __shared__ f16   xs[128 * 512];  // 128 KB, XOR-swizzled
  __shared__ f16   hs[128 * 64];   // 16 KB, XOR-swizzled
  __shared__ int   stok[128];
  __shared__ float sgate[128];

  int tid = threadIdx.x, lane = tid & 63, w = tid >> 6;
  int l15 = lane & 15, lq = lane >> 4, lk8 = lq * 8;

  const int*   tokE  = tokrec  + e * TOKENS;
  const float* gateE = gaterec + e * TOKENS;

  if (tid < 128) {
    int idx = start + tid;
    stok[tid]  = (idx < cnt) ? tokE[idx]  : -1;
    sgate[tid] = (idx < cnt) ? gateE[idx] : 0.f;
  }
  __syncthreads();

  // gather + convert x rows into LDS (row = 64 lanes x 8 f32)
  #pragma unroll
  for (int i = 0; i < 8; ++i) {
    int r = w * 8 + i;
    int trec = stok[r];
    f32x4 a = {0.f,0.f,0.f,0.f}, bv = {0.f,0.f,0.f,0.f};
    if (trec >= 0) {
      const float* p = x + (size_t)(trec & 0x3FFFFFFF) * D_ + lane * 8;
      a  = *(const f32x4*)p;
      bv = *(const f32x4*)(p + 4);
    }
    f16x8 pk;
    pk[0]=(f16)a[0];  pk[1]=(f16)a[1];  pk[2]=(f16)a[2];  pk[3]=(f16)a[3];
    pk[4]=(f16)bv[0]; pk[5]=(f16)bv[1]; pk[6]=(f16)bv[2]; pk[7]=(f16)bv[3];
    int off = (r * 1024 + lane * 16) ^ ((r & 7) << 4);
    *(f16x8*)((char*)xs + off) = pk;
  }
  __syncthreads();

  f32x4 yacc[4][4];
  #pragma unroll
  for (int mt = 0; mt < 4; ++mt)
    #pragma unroll
    for (int nt = 0; nt < 4; ++nt) {
      yacc[mt][nt][0]=0.f; yacc[mt][nt][1]=0.f; yacc[mt][nt][2]=0.f; yacc[mt][nt][3]=0.f;
    }

  int rga = w >> 2, cta = w & 3;   // stage-A role
  int rgb = w >> 3, csb = w & 7;   // stage-B role
  const f16* w1b = W1p + (size_t)e * (64 * 16 * 512);
  const f16* w2b = W2p + (size_t)e * (32 * 32 * 512);

  for (int it = 0; it < 16; ++it) {
    // ---- stage A: H[128 x 64] ----
    float b1v = b1[e * F_ + it * 64 + cta * 16 + l15];
    const f16* pA = w1b + ((size_t)(it * 4 + cta) * 16) * 512 + lane * 8;
    f32x4 h0 = {0.f,0.f,0.f,0.f}, h1 = {0.f,0.f,0.f,0.f};
    int r0b = rga * 32 + l15, r1b = r0b + 16;
    #pragma unroll
    for (int ks = 0; ks < 16; ++ks) {
      f16x8 wf = *(const f16x8*)(pA + (size_t)ks * 512);
      int k2 = (ks * 32 + lk8) * 2;
      f16x8 a0 = *(const f16x8*)((const char*)xs + ((r0b * 1024 + k2) ^ ((r0b & 7) << 4)));
      f16x8 a1 = *(const f16x8*)((const char*)xs + ((r1b * 1024 + k2) ^ ((r1b & 7) << 4)));
      h0 = __builtin_amdgcn_mfma_f32_16x16x32_f16(a0, wf, h0, 0, 0, 0);
      h1 = __builtin_amdgcn_mfma_f32_16x16x32_f16(a1, wf, h1, 0, 0, 0);
    }
    #pragma unroll
    for (int rg = 0; rg < 4; ++rg) {
      h0[rg] = gelu_f(h0[rg] + b1v);
      h1[rg] = gelu_f(h1[rg] + b1v);
    }
    __syncthreads();   // stage-B reads of previous hs done
    #pragma unroll
    for (int mt = 0; mt < 2; ++mt) {
      #pragma unroll
      for (int rg = 0; rg < 4; ++rg) {
        int row = rga * 32 + mt * 16 + lq * 4 + rg;
        int off = (row * 128 + (cta * 16 + l15) * 2) ^ ((row & 7) << 4);
        *(f16*)((char*)hs + off) = (f16)(mt ? h1[rg] : h0[rg]);
      }
    }
    __syncthreads();   // hs ready

    // ---- stage B: yacc += H @ W2 (K = 64) ----
    #pragma unroll
    for (int ks = 0; ks < 2; ++ks) {
      f16x8 wfB[4];
      #pragma unroll
      for (int nt = 0; nt < 4; ++nt)
        wfB[nt] = *(const f16x8*)(w2b + (((size_t)(csb * 4 + nt)) * 32 + it * 2 + ks) * 512 + lane * 8);
      f16x8 afr[4];
      #pragma unroll
      for (int mt = 0; mt < 4; ++mt) {
        int row = rgb * 64 + mt * 16 + l15;
        int off = (row * 128 + (ks * 32 + lk8) * 2) ^ ((row & 7) << 4);
        afr[mt] = *(const f16x8*)((const char*)hs + off);
      }
      #pragma unroll
      for (int nt = 0; nt < 4; ++nt)
        #pragma unroll
        for (int mt = 0; mt < 4; ++mt)
          yacc[mt][nt] = __builtin_amdgcn_mfma_f32_16x16x32_f16(afr[mt], wfB[nt], yacc[mt][nt], 0, 0, 0);
    }
  }

  // ---- epilogue ----
  float b2s[4];
  #pragma unroll
  for (int nt = 0; nt < 4; ++nt) b2s[nt] = b2[e * D_ + csb * 64 + nt * 16 + l15];

  if (use_rec) {
    // phase 1: gated f16 values into xs (free after last stage A)
    #pragma unroll
    for (int mt = 0; mt < 4; ++mt) {
      #pragma unroll
      for (int rg = 0; rg < 4; ++rg) {
        int row = rgb * 64 + mt * 16 + lq * 4 + rg;
        float g = sgate[row];
        #pragma unroll
        for (int nt = 0; nt < 4; ++nt) {
          int col = csb * 64 + nt * 16 + l15;
          int off = (row * 1024 + col * 2) ^ ((row & 7) << 4);
          *(f16*)((char*)xs + off) = (f16)(g * (yacc[mt][nt][rg] + b2s[nt]));
        }
      }
    }
    __syncthreads();
    // phase 2: full-row coalesced stores (rank0 -> y f32, rank1 -> rec1 f16)
    #pragma unroll
    for (int i = 0; i < 8; ++i) {
      int r = w * 8 + i;
      int trec = stok[r];
      if (trec < 0) continue;
      size_t tk = (size_t)(trec & 0x3FFFFFFF);
      f16x8 v = *(const f16x8*)((const char*)xs + ((r * 1024 + lane * 16) ^ ((r & 7) << 4)));
      if (trec & RANKBIT) {
        *(f16x8*)(rec1 + tk * D_ + lane * 8) = v;
      } else {
        f32x4 lo, hi;
        lo[0]=(float)v[0]; lo[1]=(float)v[1]; lo[2]=(float)v[2]; lo[3]=(float)v[3];
        hi[0]=(float)v[4]; hi[1]=(float)v[5]; hi[2]=(float)v[6]; hi[3]=(float)v[7];
        float* yp = y + tk * D_ + lane * 8;
        *(f32x4*)yp = lo;
        *(f32x4*)(yp + 4) = hi;
      }
    }
  } else {
    #pragma unroll
    for (int mt = 0; mt < 4; ++mt) {
      #pragma unroll
      for (int rg = 0; rg < 4; ++rg) {
        int row = rgb * 64 + mt * 16 + lq * 4 + rg;
        int trec = stok[row];
        if (trec < 0) continue;
        float g = sgate[row];
        size_t tk = (size_t)(trec & 0x3FFFFFFF);
        float* yp = y + tk * D_ + csb * 64 + l15;
        #pragma unroll
        for (int nt = 0; nt < 4; ++nt)
          atomicAdd(yp + nt * 16, g * (yacc[mt][nt][rg] + b2s[nt]));
      }
    }
  }
}

// ---------------------------------------------------------------------------
// y[t] += rec1[t]  (rank0 already in y, rank1 gated in rec1)
// ---------------------------------------------------------------------------
__global__ __launch_bounds__(256) void k_combine(const f16* __restrict__ rec1,
                                                 float* __restrict__ y)
{
  size_t i = (size_t)blockIdx.x * 256 + threadIdx.x;
  size_t n = (size_t)TOKENS * (D_ / 8);
  size_t stride = (size_t)gridDim.x * 256;
  for (; i < n; i += stride) {
    f16x8 r = *((const f16x8*)rec1 + i);
    float* yp = y + i * 8;
    f32x4 lo = *(const f32x4*)yp;
    f32x4 hi = *((const f32x4*)yp + 1);
    lo[0] += (float)r[0]; lo[1] += (float)r[1]; lo[2] += (float)r[2]; lo[3] += (float)r[3];
    hi[0] += (float)r[4]; hi[1] += (float)r[5]; hi[2] += (float)r[6]; hi[3] += (float)r[7];
    *(f32x4*)yp = lo;
    *((f32x4*)yp + 1) = hi;
  }
}

// ---------------------------------------------------------------------------
__global__ void k_aux(const int* __restrict__ gcnt, const float* __restrict__ gimp,
                      float* __restrict__ outp)
{
  if (threadIdx.x == 0) {
    float a = 0.f;
    for (int e2 = 0; e2 < E_; ++e2)
      a += ((float)gcnt[e2] * (1.f / 65536.f)) * (gimp[e2] * (1.f / 65536.f));
    outp[0] = (float)E_ * a;
  }
}

extern "C" void kernel_launch(void* const* d_in, const int* in_sizes, int n_in,
                              void* d_out, int out_size, void* d_ws, size_t ws_size,
                              hipStream_t stream)
{
  const float* x   = (const float*)d_in[0];
  const float* z   = (const float*)d_in[1];
  const float* tau = (const float*)d_in[2];
  const float* Wr  = (const float*)d_in[3];
  const float* br  = (const float*)d_in[4];
  const float* W1  = (const float*)d_in[5];
  const float* b1  = (const float*)d_in[6];
  const float* W2  = (const float*)d_in[7];
  const float* b2  = (const float*)d_in[8];
  float* out = (float*)d_out;
  char*  ws  = (char*)d_ws;

  int*   gcnt    = (int*)  (ws + OFF_CNT);
  float* gimp    = (float*)(ws + OFF_IMP);
  int*   tokrec  = (int*)  (ws + OFF_TOK);
  float* gaterec = (float*)(ws + OFF_GATE);
  f16*   W1p     = (f16*)  (ws + OFF_W1P);
  f16*   W2p     = (f16*)  (ws + OFF_W2P);
  f16*   rec1    = (f16*)  (ws + OFF_REC1);

  int use_rec = (ws_size >= WS_NEED) ? 1 : 0;

  hipMemsetAsync(ws, 0, 4096, stream);                        // counters
  if (!use_rec)
    hipMemsetAsync(d_out, 0, (size_t)out_size * 4, stream);   // y for atomics

  k_pack<<<dim3(D_/128, F_/16, E_), 256, 0, stream>>>(W1, W1p, D_, F_); // K=D, N=F
  k_pack<<<dim3(F_/128, D_/16, E_), 256, 0, stream>>>(W2, W2p, F_, D_); // K=F, N=D

  k_router<<<TOKENS / 128, 256, 0, stream>>>(x, z, tau, Wr, br, gcnt, gimp,
                                             tokrec, gaterec);

  k_mlp<<<E_ * (TOKENS / 128), 1024, 0, stream>>>(x, W1p, b1, W2p, b2, gcnt,
                                                  tokrec, gaterec, rec1, out, use_rec);

  if (use_rec)
    k_combine<<<2048, 256, 0, stream>>>(rec1, out);

  k_aux<<<1, 64, 0, stream>>>(gcnt, gimp, out + (size_t)TOKENS * D_);
}